// Round 5
// baseline (96.730 us; speedup 1.0000x reference)
//
#include <hip/hip_runtime.h>

#define K_BINS 1025
#define T_LEN  2000
#define NF     128

__device__ __forceinline__ float softplusf(float x) {
    // matches jax.nn.softplus = max(x,0) + log1p(exp(-|x|))
    return fmaxf(x, 0.0f) + log1pf(expf(-fabsf(x)));
}

// out[b2][t][4*bp + w] = sum_k w_f(k) * spec[bp][k][t],  f = b2 + 32*w
// Block = (bp-quad q, b2-quad b2q, t-chunk tc of 256). 256 thr = 4 waves.
// Wave wid = bp-local; lane owns t = 256*tc + 4*lane (one float4).
// The 4 ADJACENT filters (i=0..3) of a quad re-read overlapping rows
// back-to-back in the same wave -> L1/L2 absorbs the mel-overlap refetch.
// Epilogue: LDS [256][20] transpose per b2 -> full-64B-line float4 stores.
__global__ __launch_bounds__(256) void fb_fused(
        const float* __restrict__ spec,
        const float* __restrict__ cf,
        const float* __restrict__ bwv,
        const float* __restrict__ fs,
        float*       __restrict__ out) {
    const int q    = blockIdx.x;          // bp-quad 0..7 (id%8 -> XCD q)
    const int b2q  = blockIdx.y;          // b2-quad 0..7
    const int tc   = blockIdx.z;          // t-chunk 0..7 (256*8 = 2048 >= 2000)
    const int tid  = threadIdx.x;
    const int lane = tid & 63;
    const int wid  = tid >> 6;            // bp-local 0..3
    const int bp   = 4 * q + wid;
    const int tb   = 256 * tc + 4 * lane; // float4 t-base
    const bool tval = (tb < T_LEN);       // T_LEN%4==0 so whole float4 valid

    float4 acc[4][4];                     // [i: b2-local][w]
#pragma unroll
    for (int i = 0; i < 4; ++i)
#pragma unroll
        for (int w = 0; w < 4; ++w) acc[i][w] = make_float4(0.f, 0.f, 0.f, 0.f);

    const float* specb = spec + (size_t)bp * (K_BINS * T_LEN) + tb;

#pragma unroll
    for (int w = 0; w < 4; ++w) {
#pragma unroll
        for (int i = 0; i < 4; ++i) {
            const int f = (4 * b2q + i) + 32 * w;
            float c  = cf[f];
            float bw = softplusf(bwv[f]) + 0.001f;
            float s0 = softplusf(fs[2 * f])     + 0.1f;
            float s1 = softplusf(fs[2 * f + 1]) + 0.1f;
            float left  = c - bw * s0;
            float right = c + bw * s1;
            float invcl = 1.0f / (c - left + 1e-8f);
            float invrc = 1.0f / (right - c + 1e-8f);
            int klo = max(0, (int)ceilf(left));
            int khi = min(K_BINS - 1, (int)floorf(right));

            float4 a = acc[i][w];
            if (tval) {
                const float4* sp =
                    (const float4*)(specb + (size_t)klo * T_LEN);
                for (int k = klo; k <= khi; ++k) {
                    float fk   = (float)k;
                    float rise = (fk - left) * invcl;
                    float fall = fmaf(-(fk - c), invrc, 1.0f);
                    float wgt  = fmaxf(0.0f, fminf(rise, fall));
                    float4 v = *sp;
                    a.x = fmaf(wgt, v.x, a.x);
                    a.y = fmaf(wgt, v.y, a.y);
                    a.z = fmaf(wgt, v.z, a.z);
                    a.w = fmaf(wgt, v.w, a.w);
                    sp += 500;            // next k-row (2000 floats)
                }
            }
            acc[i][w] = a;
        }
    }

    // Epilogue: per b2-local i, transpose via LDS and store full lines.
    __shared__ float tile[256][20];       // stride 20: 16B-aligned rows, low conflict
#pragma unroll
    for (int i = 0; i < 4; ++i) {
        __syncthreads();                  // protect tile reuse
        if (tval) {
#pragma unroll
            for (int w = 0; w < 4; ++w) {
                int col = 4 * wid + w;    // f2 - 16q
                tile[4 * lane + 0][col] = acc[i][w].x;
                tile[4 * lane + 1][col] = acc[i][w].y;
                tile[4 * lane + 2][col] = acc[i][w].z;
                tile[4 * lane + 3][col] = acc[i][w].w;
            }
        }
        __syncthreads();
        const int b2 = 4 * b2q + i;
        const int c4 = tid & 3;
#pragma unroll
        for (int rr = 0; rr < 4; ++rr) {
            int tl = 64 * rr + (tid >> 2);
            int t  = 256 * tc + tl;
            if (t < T_LEN) {
                float4 v = *reinterpret_cast<const float4*>(&tile[tl][4 * c4]);
                *reinterpret_cast<float4*>(
                    out + ((size_t)b2 * T_LEN + t) * NF + 16 * q + 4 * c4) = v;
            }
        }
    }
}

extern "C" void kernel_launch(void* const* d_in, const int* in_sizes, int n_in,
                              void* d_out, int out_size, void* d_ws, size_t ws_size,
                              hipStream_t stream) {
    const float* spec = (const float*)d_in[0];   // (32, 1025, 2000) f32
    const float* cf   = (const float*)d_in[1];   // (128,)
    const float* bwv  = (const float*)d_in[2];   // (128,)
    const float* fs   = (const float*)d_in[3];   // (128, 2)
    float* out = (float*)d_out;                  // (32, 2000, 128) f32

    fb_fused<<<dim3(8, 8, 8), 256, 0, stream>>>(spec, cf, bwv, fs, out);
}

// Round 6
// 62.378 us; speedup vs baseline: 1.5507x; 1.5507x over previous
//
#include <hip/hip_runtime.h>

#define K_BINS 1025
#define T_LEN  2000
#define NF     128
#define TQ     500   // t per block (2000 = 4*500)

__device__ __forceinline__ float softplusf(float x) {
    // matches jax.nn.softplus = max(x,0) + log1p(exp(-|x|))
    return fmaxf(x, 0.0f) + log1pf(expf(-fabsf(x)));
}

// out[b2][t][4*bp + w] = sum_k w_f(k) * spec[bp][k][t],  f = b2 + 32*w
// Block = (bp-quad q, b2-quad B, t-quarter th). 1024 thr = 16 waves (w,p).
// Wave (w,p): the 4 ADJACENT filters f = 4B+32w+i for bp = 4q+p. Walks the
// UNION of the 4 supports once: one row-read feeds 4 filters (mel-overlap
// reuse in-register). Gaps (high-f quads) skipped via wave-uniform wmax test.
// 2 float4 loads/row/lane keep MLP high; 16 waves/CU TLP on top.
// Epilogue: LDS [512][17] transpose -> full 64 B line float4 stores.
__global__ __launch_bounds__(1024) void fb_fused(
        const float* __restrict__ spec,
        const float* __restrict__ cf,
        const float* __restrict__ bwv,
        const float* __restrict__ fs,
        float*       __restrict__ out) {
    const int q    = blockIdx.x;   // bp-quad 0..7 (id%8 -> XCD q)
    const int B    = blockIdx.y;   // b2-quad 0..7
    const int th   = blockIdx.z;   // t-quarter 0..3
    const int tid  = threadIdx.x;
    const int lane = tid & 63;
    const int wid  = tid >> 6;     // 0..15
    const int w    = wid >> 2;     // filter band 0..3
    const int p    = wid & 3;      // bp-local 0..3
    const int bp   = 4 * q + p;
    const int t0   = TQ * th;

    // 4 adjacent filters' params (lane-uniform)
    float lef[4], cen[4], icl[4], irc[4];
    int   klo[4], khi[4];
#pragma unroll
    for (int i = 0; i < 4; ++i) {
        const int f = 4 * B + 32 * w + i;
        float c  = cf[f];
        float bw = softplusf(bwv[f]) + 0.001f;
        float s0 = softplusf(fs[2 * f])     + 0.1f;
        float s1 = softplusf(fs[2 * f + 1]) + 0.1f;
        float left  = c - bw * s0;
        float right = c + bw * s1;
        lef[i] = left;
        cen[i] = c;
        icl[i] = 1.0f / (c - left + 1e-8f);
        irc[i] = 1.0f / (right - c + 1e-8f);
        klo[i] = max(0, (int)ceilf(left));
        khi[i] = min(K_BINS - 1, (int)floorf(right));
    }
    const int klo_u = min(min(klo[0], klo[1]), min(klo[2], klo[3]));
    const int khi_u = max(max(khi[0], khi[1]), max(khi[2], khi[3]));

    float4 acc[4][2];
#pragma unroll
    for (int i = 0; i < 4; ++i) {
        acc[i][0] = make_float4(0.f, 0.f, 0.f, 0.f);
        acc[i][1] = make_float4(0.f, 0.f, 0.f, 0.f);
    }

    const float* base = spec + (size_t)bp * (K_BINS * (size_t)T_LEN) + t0;
    const bool ok1 = (64 + lane) < (TQ / 4);   // 125 float4 per 500-t slice

    for (int k = klo_u; k <= khi_u; ++k) {
        float fk = (float)k;
        float wg[4];
        float wm = 0.0f;
#pragma unroll
        for (int i = 0; i < 4; ++i) {
            float rise = (fk - lef[i]) * icl[i];
            float fall = fmaf(-(fk - cen[i]), irc[i], 1.0f);
            wg[i] = fmaxf(0.0f, fminf(rise, fall));
            wm = fmaxf(wm, wg[i]);
        }
        if (wm > 0.0f) {                       // wave-uniform gap skip
            const float4* rp = (const float4*)(base + (size_t)k * T_LEN);
            float4 v0 = rp[lane];
            float4 v1 = make_float4(0.f, 0.f, 0.f, 0.f);
            if (ok1) v1 = rp[64 + lane];
#pragma unroll
            for (int i = 0; i < 4; ++i) {
                acc[i][0].x = fmaf(wg[i], v0.x, acc[i][0].x);
                acc[i][0].y = fmaf(wg[i], v0.y, acc[i][0].y);
                acc[i][0].z = fmaf(wg[i], v0.z, acc[i][0].z);
                acc[i][0].w = fmaf(wg[i], v0.w, acc[i][0].w);
                acc[i][1].x = fmaf(wg[i], v1.x, acc[i][1].x);
                acc[i][1].y = fmaf(wg[i], v1.y, acc[i][1].y);
                acc[i][1].z = fmaf(wg[i], v1.z, acc[i][1].z);
                acc[i][1].w = fmaf(wg[i], v1.w, acc[i][1].w);
            }
        }
    }

    // Epilogue: per i, transpose via LDS, store full 64 B lines.
    __shared__ float tile[512][17];
#pragma unroll
    for (int i = 0; i < 4; ++i) {
        __syncthreads();                       // protect tile reuse
        {
            const int col = 4 * p + w;         // f2 - 16q
            const int r0  = 4 * lane;          // group j=0: t-local 0..255
#pragma unroll
            for (int r = 0; r < 4; ++r)
                tile[r0 + r][col] = (&acc[i][0].x)[r];
            if (ok1) {
                const int r1 = 256 + 4 * lane; // group j=1: t-local 256..499
#pragma unroll
                for (int r = 0; r < 4; ++r)
                    tile[r1 + r][col] = (&acc[i][1].x)[r];
            }
        }
        __syncthreads();
        const int b2 = 4 * B + i;
        const int c4 = tid & 3;
#pragma unroll
        for (int rr = 0; rr < 2; ++rr) {
            int tl = 256 * rr + (tid >> 2);
            if (tl < TQ) {
                float4 v = make_float4(tile[tl][4 * c4 + 0], tile[tl][4 * c4 + 1],
                                       tile[tl][4 * c4 + 2], tile[tl][4 * c4 + 3]);
                *reinterpret_cast<float4*>(
                    out + ((size_t)b2 * T_LEN + t0 + tl) * NF + 16 * q + 4 * c4) = v;
            }
        }
    }
}

extern "C" void kernel_launch(void* const* d_in, const int* in_sizes, int n_in,
                              void* d_out, int out_size, void* d_ws, size_t ws_size,
                              hipStream_t stream) {
    const float* spec = (const float*)d_in[0];   // (32, 1025, 2000) f32
    const float* cf   = (const float*)d_in[1];   // (128,)
    const float* bwv  = (const float*)d_in[2];   // (128,)
    const float* fs   = (const float*)d_in[3];   // (128, 2)
    float* out = (float*)d_out;                  // (32, 2000, 128) f32

    fb_fused<<<dim3(8, 8, 4), 1024, 0, stream>>>(spec, cf, bwv, fs, out);
}

// Round 7
// 61.914 us; speedup vs baseline: 1.5623x; 1.0075x over previous
//
#include <hip/hip_runtime.h>

#define K_BINS 1025
#define T_LEN  2000
#define NF     128
#define TQ     500   // t per block (2000 = 4*500)

__device__ __forceinline__ float softplusf(float x) {
    // matches jax.nn.softplus = max(x,0) + log1p(exp(-|x|))
    return fmaxf(x, 0.0f) + log1pf(expf(-fabsf(x)));
}

// out[b2][t][4*bp + w] = sum_k w_f(k) * spec[bp][k][t],  f = b2 + 32*w
// Block = (bp-quad q, b2-quad B, t-quarter th). 1024 thr = 16 waves (w,p).
// Wave (w,p): 4 ADJACENT filters f = 4B+32w+i for bp = 4q+p, walking the
// MERGED RUNS of their supports (<=4 contiguous intervals -> branch-free
// inner loop, gaps skipped exactly) with a 2-deep software pipeline:
// row k+1's loads issue before row k's weights/FMAs -> compiler emits
// counted vmcnt, ~4 KiB in flight per wave at all times.
// Epilogue: LDS [512][17] transpose -> full 64 B line float4 stores.
__global__ __launch_bounds__(1024) void fb_fused(
        const float* __restrict__ spec,
        const float* __restrict__ cf,
        const float* __restrict__ bwv,
        const float* __restrict__ fs,
        float*       __restrict__ out) {
    const int q    = blockIdx.x;   // bp-quad 0..7 (id%8 -> XCD q)
    const int B    = blockIdx.y;   // b2-quad 0..7
    const int th   = blockIdx.z;   // t-quarter 0..3
    const int tid  = threadIdx.x;
    const int lane = tid & 63;
    const int wid  = tid >> 6;     // 0..15
    const int w    = wid >> 2;     // filter band 0..3
    const int p    = wid & 3;      // bp-local 0..3
    const int bp   = 4 * q + p;
    const int t0   = TQ * th;

    // 4 adjacent filters' params (lane-uniform)
    float icl[4], irc[4], Af[4], Bf[4];
    int   klo[4], khi[4];
#pragma unroll
    for (int i = 0; i < 4; ++i) {
        const int f = 4 * B + 32 * w + i;
        float c  = cf[f];
        float bw = softplusf(bwv[f]) + 0.001f;
        float s0 = softplusf(fs[2 * f])     + 0.1f;
        float s1 = softplusf(fs[2 * f + 1]) + 0.1f;
        float left  = c - bw * s0;
        float right = c + bw * s1;
        icl[i] = 1.0f / (c - left + 1e-8f);
        irc[i] = 1.0f / (right - c + 1e-8f);
        Af[i]  = left * icl[i];            // rise = fk*icl - Af
        Bf[i]  = fmaf(c, irc[i], 1.0f);    // fall = Bf - fk*irc
        klo[i] = max(0, (int)ceilf(left));
        khi[i] = min(K_BINS - 1, (int)floorf(right));
    }

    // merge supports into <=4 contiguous runs (klo ascending by construction)
    int rs[4], re[4], nr = 0;
    {
        int cs = klo[0], ce = khi[0];
#pragma unroll
        for (int i = 1; i < 4; ++i) {
            if (klo[i] <= ce + 1) ce = max(ce, khi[i]);
            else { rs[nr] = cs; re[nr] = ce; ++nr; cs = klo[i]; ce = khi[i]; }
        }
        rs[nr] = cs; re[nr] = ce; ++nr;
    }

    float4 acc[4][2];
#pragma unroll
    for (int i = 0; i < 4; ++i) {
        acc[i][0] = make_float4(0.f, 0.f, 0.f, 0.f);
        acc[i][1] = make_float4(0.f, 0.f, 0.f, 0.f);
    }

    const float4* base4 =
        (const float4*)(spec + (size_t)bp * (K_BINS * (size_t)T_LEN) + t0);
    const bool ok1 = (64 + lane) < (TQ / 4);   // 125 float4 per 500-t slice

    // 2-deep pipelined walk
    int rcur = 0;
    int kcur = rs[0];
    float4 v0 = base4[(size_t)kcur * 500 + lane];
    float4 v1 = make_float4(0.f, 0.f, 0.f, 0.f);
    if (ok1) v1 = base4[(size_t)kcur * 500 + 64 + lane];

    while (kcur >= 0) {
        // next cursor (wave-uniform scalar)
        int knext, rnext = rcur;
        if (kcur + 1 <= re[rcur])      knext = kcur + 1;
        else if (rcur + 1 < nr)        { rnext = rcur + 1; knext = rs[rnext]; }
        else                           knext = -1;

        // prefetch next row before consuming current
        float4 n0, n1;
        if (knext >= 0) {
            const float4* np = base4 + (size_t)knext * 500;
            n0 = np[lane];
            if (ok1) n1 = np[64 + lane];
        }

        float fk = (float)kcur;
#pragma unroll
        for (int i = 0; i < 4; ++i) {
            float rise = fmaf(fk, icl[i], -Af[i]);
            float fall = fmaf(-fk, irc[i], Bf[i]);
            float wg   = fmaxf(0.0f, fminf(rise, fall));
            acc[i][0].x = fmaf(wg, v0.x, acc[i][0].x);
            acc[i][0].y = fmaf(wg, v0.y, acc[i][0].y);
            acc[i][0].z = fmaf(wg, v0.z, acc[i][0].z);
            acc[i][0].w = fmaf(wg, v0.w, acc[i][0].w);
            acc[i][1].x = fmaf(wg, v1.x, acc[i][1].x);
            acc[i][1].y = fmaf(wg, v1.y, acc[i][1].y);
            acc[i][1].z = fmaf(wg, v1.z, acc[i][1].z);
            acc[i][1].w = fmaf(wg, v1.w, acc[i][1].w);
        }
        v0 = n0; v1 = n1;
        kcur = knext; rcur = rnext;
    }

    // Epilogue: per i, transpose via LDS, store full 64 B lines.
    __shared__ float tile[512][17];
#pragma unroll
    for (int i = 0; i < 4; ++i) {
        __syncthreads();                       // protect tile reuse
        {
            const int col = 4 * p + w;         // f2 - 16q
            const int r0  = 4 * lane;
#pragma unroll
            for (int r = 0; r < 4; ++r)
                tile[r0 + r][col] = (&acc[i][0].x)[r];
            if (ok1) {
                const int r1 = 256 + 4 * lane;
#pragma unroll
                for (int r = 0; r < 4; ++r)
                    tile[r1 + r][col] = (&acc[i][1].x)[r];
            }
        }
        __syncthreads();
        const int b2 = 4 * B + i;
        const int c4 = tid & 3;
#pragma unroll
        for (int rr = 0; rr < 2; ++rr) {
            int tl = 256 * rr + (tid >> 2);
            if (tl < TQ) {
                float4 v = make_float4(tile[tl][4 * c4 + 0], tile[tl][4 * c4 + 1],
                                       tile[tl][4 * c4 + 2], tile[tl][4 * c4 + 3]);
                *reinterpret_cast<float4*>(
                    out + ((size_t)b2 * T_LEN + t0 + tl) * NF + 16 * q + 4 * c4) = v;
            }
        }
    }
}

extern "C" void kernel_launch(void* const* d_in, const int* in_sizes, int n_in,
                              void* d_out, int out_size, void* d_ws, size_t ws_size,
                              hipStream_t stream) {
    const float* spec = (const float*)d_in[0];   // (32, 1025, 2000) f32
    const float* cf   = (const float*)d_in[1];   // (128,)
    const float* bwv  = (const float*)d_in[2];   // (128,)
    const float* fs   = (const float*)d_in[3];   // (128, 2)
    float* out = (float*)d_out;                  // (32, 2000, 128) f32

    fb_fused<<<dim3(8, 8, 4), 1024, 0, stream>>>(spec, cf, bwv, fs, out);
}